// Round 7
// baseline (566.140 us; speedup 1.0000x reference)
//
#include <hip/hip_runtime.h>

#define NN 8192
#define STEPS 64
#define DECAYF 0.9f
#define THRESHF 1.0f
#define K_MAX 384            // ELL row capacity = 2 segments x 192
#define K_SEG 192            // per-half-row segment (nnz ~129 +/- 11, +5.6 sigma)
#define KITER 24             // 384 / 16 lanes per row
#define LROWS 32             // rows per block
#define LPITCH 385           // LDS ELL row pitch in u64 (+1 pad: bank spread)

#define CBLOCKS 256          // one block per CU; regular launch
#define STHREADS 576         // 9 waves: wave 0 = poller, 1..8 compute+publish
#define MBSTRIDE 16          // u64 per mailbox entry = 128 B (R15 dense regressed)

#define CHUNKF 256           // floats per DMA chunk = 1 KB (64 lanes x 16 B)

typedef unsigned long long u64;
typedef unsigned int u32;

// R20: alias-separated DMA ping-pong. R18/R19 failed because all DMA slots
// shared ONE LDS object: any ds_read of it forced a conservative
// compiler-inserted vmcnt(0) (and asm "memory" clobber does the same),
// collapsing pipeline depth to ~0 in every variant. Now four DISTINCT
// __shared__ buffers rotate as DMA targets (compile-time bound, unroll x4):
// alias analysis lets SIInsertWaitcnts emit counted per-object waits, so
// 3 x 1 KB stay in flight per wave with zero inline asm. Each compute wave
// extracts ITS OWN 4 rows -> no cross-wave ELL handoff -> the post-
// extraction __syncthreads is gone (barrier moved to top, pre-extraction);
// wave 0 polls step-0 mailboxes DURING extraction (peers publish f0 first).
// Step loop + poller: R13-verbatim (198.6 us measured).
__device__ __forceinline__ void pub_store(u64* p, u64 v) {
    __hip_atomic_store(p, v, __ATOMIC_RELAXED, __HIP_MEMORY_SCOPE_AGENT);
}
__device__ __forceinline__ u64 pub_load(const u64* p) {
    return __hip_atomic_load(p, __ATOMIC_RELAXED, __HIP_MEMORY_SCOPE_AGENT);
}
__device__ __forceinline__ void dma16(const float* g, float* l) {
    __builtin_amdgcn_global_load_lds(
        (const __attribute__((address_space(1))) float*)g,
        (__attribute__((address_space(3))) float*)l, 16, 0, 0);
}

__global__ __launch_bounds__(STHREADS) void spiking_fused(
        const float* __restrict__ W,
        const float* __restrict__ f0,
        const float* __restrict__ v0,
        float* __restrict__ out,
        u64* __restrict__ fdata) {       // [2][CBLOCKS][MBSTRIDE]
    __shared__ u64 lds_ell[LROWS * LPITCH];          // 98.6 KB packed ELL
    __shared__ __align__(16) float bufA[8 * CHUNKF]; // 8 KB (1 KB per wave)
    __shared__ __align__(16) float bufB[8 * CHUNKF]; // 8 KB
    __shared__ __align__(16) float bufC[8 * CHUNKF]; // 8 KB
    __shared__ __align__(16) float bufD[8 * CHUNKF]; // 8 KB
    __shared__ u32 lds_fbits[2][CBLOCKS];            // 2 KB, dbuf by parity
    __shared__ u32 lds_spike[8];                     // bits4 per compute wave
    __shared__ int lds_cnt[STEPS];                   // per-step arrive counters
    __shared__ int lds_flag;                         // monotonic: inputs ready

    const int tid  = threadIdx.x;
    const int wave = tid >> 6;
    const int lane = tid & 63;
    const int bid  = blockIdx.x;

    if (tid < STEPS) lds_cnt[tid] = 0;
    if (tid == 0) lds_flag = 0;

    // publish own f0 word (tag 1, slot 0) ASAP
    if (wave == 0) {
        float f = (lane < 32) ? f0[bid * 32 + lane] : 0.0f;
        u64 m = __ballot(f != 0.0f);
        if (lane == 0)
            pub_store(&fdata[(size_t)bid * MBSTRIDE],
                      (1ull << 32) | (u32)(m & 0xffffffffull));
    }
    __syncthreads();   // only barrier: control-var init (pre-extraction,
                       // nothing outstanding to drain)

    if (wave == 0) {
        // ===== PURE POLLER (R13 verbatim) — starts during extraction ======
        for (int s = 0; s < STEPS; ++s) {
            const u64* slot = fdata + (size_t)(s & 1) * CBLOCKS * MBSTRIDE;
            const u32 want = (u32)(s + 1);
            u32* fb = lds_fbits[s & 1];
            u32 pend = 0xFu;                 // 4 words per lane outstanding
            for (;;) {
                #pragma unroll
                for (int k = 0; k < 4; ++k) {
                    if ((pend >> k) & 1u) {
                        u64 w = pub_load(&slot[(size_t)(lane + 64 * k) * MBSTRIDE]);
                        if ((u32)(w >> 32) == want) {
                            fb[lane + 64 * k] = (u32)w;   // stash on arrival
                            pend &= ~(1u << k);
                        }
                    }
                }
                if (__all(pend == 0)) break;
                __builtin_amdgcn_s_sleep(2);   // ~128 cyc: cut L3 read pressure
            }
            if (lane == 0)
                __hip_atomic_store(&lds_flag, s + 1, __ATOMIC_RELEASE,
                                   __HIP_MEMORY_SCOPE_WORKGROUP);
        }
    } else {
        const int gx   = wave - 1;               // 0..7
        const int rl0  = gx << 2;                // this wave's first local row

        // ===== Phase 0: extract OWN 4 rows (8 half-rows = 128 x 1KB chunks)
        // via 4-object DMA ping-pong. chunk t: half-row t>>4, piece t&15.
        {
            const u64 lmask = (1ull << lane) - 1ull;
            float* const myA = bufA + gx * CHUNKF;
            float* const myB = bufB + gx * CHUNKF;
            float* const myC = bufC + gx * CHUNKF;
            float* const myD = bufD + gx * CHUNKF;

            auto issue = [&](int t, float* obj) {
                if (t < 128) {
                    const int hrl = t >> 4, c = t & 15;
                    const int row = rl0 + (hrl >> 1);
                    const float* src = W
                        + (size_t)(bid * LROWS + row) * NN
                        + (hrl & 1) * (NN / 2) + c * CHUNKF + lane * 4;
                    dma16(src, obj + lane * 4);
                }
            };
            int base = 0;
            auto compact = [&](int t, const float* obj) {
                const int hrl = t >> 4, c = t & 15;
                const int rloc = rl0 + (hrl >> 1);
                const int half = hrl & 1;
                u64* pr = lds_ell + rloc * LPITCH + half * K_SEG;
                if (c == 0) base = 0;
                float4 w4 = *(const float4*)(obj + lane * 4);  // compiler
                    // emits a counted vmcnt wait for THIS object's DMA only
                const int col0 = half * (NN / 2) + c * CHUNKF + lane * 4;
                #pragma unroll
                for (int comp = 0; comp < 4; ++comp) {
                    float val = (comp == 0) ? w4.x : (comp == 1) ? w4.y
                              : (comp == 2) ? w4.z : w4.w;
                    u64 m = __ballot(val != 0.0f);
                    if (val != 0.0f) {
                        int idx = base + __popcll(m & lmask);
                        if (idx < K_SEG)             // +5.6 sigma guard
                            pr[idx] = ((u64)(u32)(col0 + comp) << 32)
                                    | (u64)__float_as_uint(val);
                    }
                    base += __popcll(m);
                }
                if (c == 15) {                       // zero-pad this segment
                    const int cap = (base < K_SEG) ? base : K_SEG;
                    for (int j = cap + lane; j < K_SEG; j += 64) pr[j] = 0ull;
                }
            };

            issue(0, myA); issue(1, myB); issue(2, myC);
            for (int t = 0; t < 128; t += 4) {
                issue(t + 3, myD); compact(t,     myA);
                issue(t + 4, myA); compact(t + 1, myB);
                issue(t + 5, myB); compact(t + 2, myC);
                issue(t + 6, myC); compact(t + 3, myD);
            }
        }

        // ===== COMPUTE (waves 1..8, own 4 rows); last wave publishes =======
        const int rloc = rl0 + (lane >> 4);      // local row 0..31
        const int row  = bid * LROWS + rloc;
        const int l16  = lane & 15;

        // own LDS ELL -> registers (no barrier needed: own-wave data)
        u32 ecol[KITER]; float eval[KITER];
        const u64* pr = lds_ell + rloc * LPITCH;
        #pragma unroll
        for (int k = 0; k < KITER; ++k) {
            u64 p = pr[l16 + 16 * k];
            ecol[k] = (u32)(p >> 32);
            eval[k] = __uint_as_float((u32)p);
        }
        float vreg = v0[row];                    // identical across the 16 lanes

        for (int s = 0; s < STEPS; ++s) {
            while (__hip_atomic_load(&lds_flag, __ATOMIC_ACQUIRE,
                                     __HIP_MEMORY_SCOPE_WORKGROUP) < s + 1) {}
            const u32* fb = lds_fbits[s & 1];

            // gather with 3 independent fp64 accumulators (short dep chains)
            double a0 = 0.0, a1 = 0.0, a2 = 0.0;
            #pragma unroll
            for (int k = 0; k < KITER; k += 3) {
                u32 c0 = ecol[k],     w0 = fb[c0 >> 5];
                u32 c1 = ecol[k + 1], w1 = fb[c1 >> 5];
                u32 c2 = ecol[k + 2], w2 = fb[c2 >> 5];
                a0 += (double)(((w0 >> (c0 & 31)) & 1u) ? eval[k]     : 0.0f);
                a1 += (double)(((w1 >> (c1 & 31)) & 1u) ? eval[k + 1] : 0.0f);
                a2 += (double)(((w2 >> (c2 & 31)) & 1u) ? eval[k + 2] : 0.0f);
            }
            double acc = (a0 + a1) + a2;
            #pragma unroll
            for (int m = 8; m >= 1; m >>= 1)     // 16-lane butterfly
                acc += __shfl_xor(acc, m, 64);

            float u  = (float)acc;
            float vv = __fadd_rn(__fmul_rn(DECAYF, vreg), u);
            int fire = (vv >= THRESHF);
            vreg = fire ? 0.0f : vv;

            // ---- publish path FIRST (critical chain), out[] store after ----
            u64 bal = __ballot(fire);            // uniform within 16-lane groups
            int old = -1;
            if (lane == 0) {
                u32 bits4 = ((u32)(bal       ) & 1u)
                          | (((u32)(bal >> 16) & 1u) << 1)
                          | (((u32)(bal >> 32) & 1u) << 2)
                          | (((u32)(bal >> 48) & 1u) << 3);
                __hip_atomic_store(&lds_spike[gx], bits4, __ATOMIC_RELAXED,
                                   __HIP_MEMORY_SCOPE_WORKGROUP);
                old = __hip_atomic_fetch_add(&lds_cnt[s], 1, __ATOMIC_ACQ_REL,
                                             __HIP_MEMORY_SCOPE_WORKGROUP);
            }
            old = __shfl(old, 0, 64);
            if (old == 7) {                      // 8th (last) compute wave
                u32 b = (lane < 8) ? ((lds_spike[lane] & 0xFu) << (4 * lane)) : 0u;
                b |= __shfl_xor(b, 1, 64);
                b |= __shfl_xor(b, 2, 64);
                b |= __shfl_xor(b, 4, 64);
                if (lane == 0)
                    pub_store(&fdata[((size_t)((s + 1) & 1) * CBLOCKS + bid) * MBSTRIDE],
                              ((u64)(u32)(s + 2) << 32) | b);
            }

            if (l16 == 0)
                out[(size_t)s * NN + row] = fire ? 1.0f : 0.0f;
        }
    }
}

extern "C" void kernel_launch(void* const* d_in, const int* in_sizes, int n_in,
                              void* d_out, int out_size, void* d_ws, size_t ws_size,
                              hipStream_t stream) {
    const float* W  = (const float*)d_in[0];
    const float* f0 = (const float*)d_in[1];
    const float* v0 = (const float*)d_in[2];
    float* out = (float*)d_out;

    // workspace: padded mailbox only (64 KB); 0xAA poison != any tag 1..66
    u64* fdata = (u64*)d_ws;

    spiking_fused<<<dim3(CBLOCKS), dim3(STHREADS), 0, stream>>>(
        W, f0, v0, out, fdata);
}

// Round 8
// 556.752 us; speedup vs baseline: 1.0169x; 1.0169x over previous
//
#include <hip/hip_runtime.h>

#define NN 8192
#define STEPS 64
#define DECAYF 0.9f
#define THRESHF 1.0f
#define K_MAX 384            // ELL row capacity = 2 segments x 192
#define K_SEG 192            // per-half-row segment (nnz ~129 +/- 11, +5.6 sigma)
#define KITER 24             // 384 / 16 lanes per row
#define LROWS 32             // rows per block
#define LPITCH 385           // LDS ELL row pitch in u64 (+1 pad: bank spread)

#define CBLOCKS 256          // one block per CU; regular launch
#define STHREADS 576         // 9 waves: wave 0 = poller, 1..8 compute+publish
#define MBSTRIDE 16          // u64 per mailbox entry = 128 B (R15 dense regressed)

typedef unsigned long long u64;
typedef unsigned int u32;

// R21: batched-ballot compaction. R16..R20 established extraction is NOT
// load-bound (5 load-mechanism variants, incl. 26-wave standalone, all
// ~2.5 TB/s): the common factor is the PER-FLOAT serial ballot chain
// (v_cmp->vcc->mask->popcount->base), ~4 cross-domain hazard hops per
// element, 64 serial rounds per half-row. Now the 4 ballots of a float4
// issue independently; per-lane slots derive from base + popcount
// combinations (independent VALU); base advances ONCE per float4 ->
// serial chain ~4x shorter. Everything else byte-identical to R16
// (best fused, 302.8us): 9-wave pool, plain loads, R13 poller/steps.
__device__ __forceinline__ void pub_store(u64* p, u64 v) {
    __hip_atomic_store(p, v, __ATOMIC_RELAXED, __HIP_MEMORY_SCOPE_AGENT);
}
__device__ __forceinline__ u64 pub_load(const u64* p) {
    return __hip_atomic_load(p, __ATOMIC_RELAXED, __HIP_MEMORY_SCOPE_AGENT);
}

__global__ __launch_bounds__(STHREADS) void spiking_fused(
        const float* __restrict__ W,
        const float* __restrict__ f0,
        const float* __restrict__ v0,
        float* __restrict__ out,
        u64* __restrict__ fdata) {       // [2][CBLOCKS][MBSTRIDE]
    __shared__ u64 lds_ell[LROWS * LPITCH];  // 98.5 KB packed ELL, this block
    __shared__ u32 lds_fbits[2][CBLOCKS];    // 2 KB, dbuf by parity
    __shared__ u32 lds_spike[8];             // bits4 per compute wave
    __shared__ int lds_cnt[STEPS];           // per-step arrive counters
    __shared__ int lds_flag;                 // monotonic: inputs ready

    const int tid  = threadIdx.x;
    const int wave = tid >> 6;
    const int lane = tid & 63;
    const int bid  = blockIdx.x;

    if (tid < STEPS) lds_cnt[tid] = 0;
    if (tid == 0) lds_flag = 0;

    // publish own f0 word (tag 1, slot 0) ASAP — lands while we extract
    if (wave == 0) {
        float f = (lane < 32) ? f0[bid * 32 + lane] : 0.0f;
        u64 m = __ballot(f != 0.0f);
        if (lane == 0)
            pub_store(&fdata[(size_t)bid * MBSTRIDE],
                      (1ull << 32) | (u32)(m & 0xffffffffull));
    }

    // ===== Phase 0: all 9 waves extract this block's 32 rows -> LDS ELL ====
    // 64 half-rows / 9 waves; half-row = 4096 cols = 16 float4/lane.
    {
        const u64 lmask = (1ull << lane) - 1ull;
        for (int hr = wave; hr < 2 * LROWS; hr += 9) {
            const int rloc = hr >> 1;
            const int half = hr & 1;
            const int cbase = half * (NN / 2);
            const float4* wr4 = (const float4*)
                (W + (size_t)(bid * LROWS + rloc) * NN + cbase);
            u64* pr = lds_ell + rloc * LPITCH + half * K_SEG;

            float4 wv[16];
            #pragma unroll
            for (int i = 0; i < 16; ++i)
                wv[i] = wr4[lane + 64 * i];

            int base = 0;
            #pragma unroll
            for (int i = 0; i < 16; ++i) {
                const int col0 = cbase + (lane + 64 * i) * 4;
                const float4 w = wv[i];
                // 4 independent ballots (no serial chain between them)
                u64 m0 = __ballot(w.x != 0.0f);
                u64 m1 = __ballot(w.y != 0.0f);
                u64 m2 = __ballot(w.z != 0.0f);
                u64 m3 = __ballot(w.w != 0.0f);
                int p0 = __popcll(m0), p1 = __popcll(m1),
                    p2 = __popcll(m2), p3 = __popcll(m3);
                int i0 = base + __popcll(m0 & lmask);
                int i1 = base + p0 + __popcll(m1 & lmask);
                int i2 = base + p0 + p1 + __popcll(m2 & lmask);
                int i3 = base + p0 + p1 + p2 + __popcll(m3 & lmask);
                if (w.x != 0.0f && i0 < K_SEG)       // +5.6 sigma guard
                    pr[i0] = ((u64)(u32)(col0 + 0) << 32)
                           | (u64)__float_as_uint(w.x);
                if (w.y != 0.0f && i1 < K_SEG)
                    pr[i1] = ((u64)(u32)(col0 + 1) << 32)
                           | (u64)__float_as_uint(w.y);
                if (w.z != 0.0f && i2 < K_SEG)
                    pr[i2] = ((u64)(u32)(col0 + 2) << 32)
                           | (u64)__float_as_uint(w.z);
                if (w.w != 0.0f && i3 < K_SEG)
                    pr[i3] = ((u64)(u32)(col0 + 3) << 32)
                           | (u64)__float_as_uint(w.w);
                base += p0 + p1 + p2 + p3;           // ONE serial update/float4
            }
            const int cap = (base < K_SEG) ? base : K_SEG;
            for (int j = cap + lane; j < K_SEG; j += 64) pr[j] = 0ull;
        }
    }
    __syncthreads();   // only barrier: ELL + control vars ready

    if (wave == 0) {
        // ===== PURE POLLER (R13 verbatim): fresh-check, stash, backoff =====
        for (int s = 0; s < STEPS; ++s) {
            const u64* slot = fdata + (size_t)(s & 1) * CBLOCKS * MBSTRIDE;
            const u32 want = (u32)(s + 1);
            u32* fb = lds_fbits[s & 1];
            u32 pend = 0xFu;                 // 4 words per lane outstanding
            for (;;) {
                #pragma unroll
                for (int k = 0; k < 4; ++k) {
                    if ((pend >> k) & 1u) {
                        u64 w = pub_load(&slot[(size_t)(lane + 64 * k) * MBSTRIDE]);
                        if ((u32)(w >> 32) == want) {
                            fb[lane + 64 * k] = (u32)w;   // stash on arrival
                            pend &= ~(1u << k);
                        }
                    }
                }
                if (__all(pend == 0)) break;
                __builtin_amdgcn_s_sleep(2);   // ~128 cyc: cut L3 read pressure
            }
            if (lane == 0)
                __hip_atomic_store(&lds_flag, s + 1, __ATOMIC_RELEASE,
                                   __HIP_MEMORY_SCOPE_WORKGROUP);
        }
    } else {
        // ===== COMPUTE (waves 1..8, 4 rows each); last wave publishes =====
        const int g    = wave - 1;               // 0..7
        const int rloc = g * 4 + (lane >> 4);    // local row 0..31
        const int row  = bid * LROWS + rloc;
        const int l16  = lane & 15;

        // one-time LDS ELL -> registers
        u32 ecol[KITER]; float eval[KITER];
        const u64* pr = lds_ell + rloc * LPITCH;
        #pragma unroll
        for (int k = 0; k < KITER; ++k) {
            u64 p = pr[l16 + 16 * k];
            ecol[k] = (u32)(p >> 32);
            eval[k] = __uint_as_float((u32)p);
        }
        float vreg = v0[row];                    // identical across the 16 lanes

        for (int s = 0; s < STEPS; ++s) {
            while (__hip_atomic_load(&lds_flag, __ATOMIC_ACQUIRE,
                                     __HIP_MEMORY_SCOPE_WORKGROUP) < s + 1) {}
            const u32* fb = lds_fbits[s & 1];

            // gather with 3 independent fp64 accumulators (short dep chains)
            double a0 = 0.0, a1 = 0.0, a2 = 0.0;
            #pragma unroll
            for (int k = 0; k < KITER; k += 3) {
                u32 c0 = ecol[k],     w0 = fb[c0 >> 5];
                u32 c1 = ecol[k + 1], w1 = fb[c1 >> 5];
                u32 c2 = ecol[k + 2], w2 = fb[c2 >> 5];
                a0 += (double)(((w0 >> (c0 & 31)) & 1u) ? eval[k]     : 0.0f);
                a1 += (double)(((w1 >> (c1 & 31)) & 1u) ? eval[k + 1] : 0.0f);
                a2 += (double)(((w2 >> (c2 & 31)) & 1u) ? eval[k + 2] : 0.0f);
            }
            double acc = (a0 + a1) + a2;
            #pragma unroll
            for (int m = 8; m >= 1; m >>= 1)     // 16-lane butterfly
                acc += __shfl_xor(acc, m, 64);

            float u  = (float)acc;
            float vv = __fadd_rn(__fmul_rn(DECAYF, vreg), u);
            int fire = (vv >= THRESHF);
            vreg = fire ? 0.0f : vv;

            // ---- publish path FIRST (critical chain), out[] store after ----
            u64 bal = __ballot(fire);            // uniform within 16-lane groups
            int old = -1;
            if (lane == 0) {
                u32 bits4 = ((u32)(bal       ) & 1u)
                          | (((u32)(bal >> 16) & 1u) << 1)
                          | (((u32)(bal >> 32) & 1u) << 2)
                          | (((u32)(bal >> 48) & 1u) << 3);
                __hip_atomic_store(&lds_spike[g], bits4, __ATOMIC_RELAXED,
                                   __HIP_MEMORY_SCOPE_WORKGROUP);
                old = __hip_atomic_fetch_add(&lds_cnt[s], 1, __ATOMIC_ACQ_REL,
                                             __HIP_MEMORY_SCOPE_WORKGROUP);
            }
            old = __shfl(old, 0, 64);
            if (old == 7) {                      // 8th (last) compute wave
                u32 b = (lane < 8) ? ((lds_spike[lane] & 0xFu) << (4 * lane)) : 0u;
                b |= __shfl_xor(b, 1, 64);
                b |= __shfl_xor(b, 2, 64);
                b |= __shfl_xor(b, 4, 64);
                if (lane == 0)
                    pub_store(&fdata[((size_t)((s + 1) & 1) * CBLOCKS + bid) * MBSTRIDE],
                              ((u64)(u32)(s + 2) << 32) | b);
            }

            if (l16 == 0)
                out[(size_t)s * NN + row] = fire ? 1.0f : 0.0f;
        }
    }
}

extern "C" void kernel_launch(void* const* d_in, const int* in_sizes, int n_in,
                              void* d_out, int out_size, void* d_ws, size_t ws_size,
                              hipStream_t stream) {
    const float* W  = (const float*)d_in[0];
    const float* f0 = (const float*)d_in[1];
    const float* v0 = (const float*)d_in[2];
    float* out = (float*)d_out;

    // workspace: padded mailbox only (64 KB); 0xAA poison != any tag 1..66
    u64* fdata = (u64*)d_ws;

    spiking_fused<<<dim3(CBLOCKS), dim3(STHREADS), 0, stream>>>(
        W, f0, v0, out, fdata);
}